// Round 14
// baseline (286.132 us; speedup 1.0000x reference)
//
#include <hip/hip_runtime.h>
#include <math.h>

constexpr int N_NODES = 20000;
constexpr int DIM = 512;       // NODE_DIM == HIDDEN
constexpr int NG = 64;
constexpr int CAP = 64;        // padded adjacency capacity (avg deg 16, max ~40, >12 sigma)
constexpr int KCH = 128;       // U-GEMM k-chunk
constexpr int NCHUNK = (N_NODES + KCH - 1) / KCH;  // 157 (last chunk kmax=32, %4==0)
constexpr int RSPLIT = 4;
constexpr int CPS = (NCHUNK + RSPLIT - 1) / RSPLIT; // 40
constexpr int CGS = 32;        // cgpad stride (floats) -> 128B, one cacheline per graph
constexpr int NODE_BLOCKS = (N_NODES + 3) / 4;      // 5000
constexpr int GEMM_TILES = 17 * 4;                  // 68 tiles for 513x256 output
constexpr int EDGE_BLOCKS = 1250;                   // 320000 edges / 256

// ---------------- misc ----------------
__device__ __forceinline__ int lower_bound_i(const int* __restrict__ a, int n, int v) {
  int lo = 0, hi = n;
  while (lo < hi) {
    int mid = (lo + hi) >> 1;
    if (a[mid] < v) lo = mid + 1; else hi = mid;
  }
  return lo;
}

// wT[j][g] = one-hot(batch[j]); cursor[j]=0; block 0: ng[g], cgpad zero
__global__ __launch_bounds__(256) void node_init(const int* __restrict__ batch,
                                                 float* __restrict__ wT,
                                                 int* __restrict__ cursor,
                                                 float* __restrict__ ng,
                                                 float* __restrict__ cgpad, int n_nodes) {
  int node = blockIdx.x * 4 + (threadIdx.x >> 6);
  int g = threadIdx.x & 63;
  if (node < n_nodes) {
    int b = batch[node];
    wT[(size_t)node * 64 + g] = (g == b) ? 1.f : 0.f;
    if (g == 0) cursor[node] = 0;
  }
  if (blockIdx.x == 0 && threadIdx.x < 64) {
    int gg = threadIdx.x;
    int s0 = lower_bound_i(batch, n_nodes, gg);
    int e0 = lower_bound_i(batch, n_nodes, gg + 1);
    ng[gg] = (float)(e0 - s0);
    cgpad[gg * CGS] = 0.f;
  }
}

// ---- shared-memory GEMM tile body: C[M,N] = [A0; extraRow] @ B, one 32x64 tile ----
__device__ void gemm_stack_tile(const float* __restrict__ A0, const float* __restrict__ extra,
                                const float* __restrict__ B, float* __restrict__ C,
                                int M, int N, int K, int R0, int tile,
                                float* As, float* Bs, int tid) {
  int bm = (tile >> 2) * 32;   // 0..16 -> 32-row tile
  int bn = (tile & 3) * 64;    // 0..3  -> 64-col tile
  int tx = tid & 15;
  int ty = tid >> 4;
  int ar = tid >> 3;
  int ac = (tid & 7) * 2;
  int br = tid >> 4;
  int bc = (tid & 15) * 4;
  float acc[2][4] = {};
  for (int k0 = 0; k0 < K; k0 += 16) {
    int row = bm + ar;
    float2 av = make_float2(0.f, 0.f);
    if (row < R0)       av = *(const float2*)(A0 + (size_t)row * K + k0 + ac);
    else if (row == R0) av = *(const float2*)(extra + k0 + ac);
    As[(ac + 0) * 33 + ar] = av.x;
    As[(ac + 1) * 33 + ar] = av.y;
    float4 bv = *(const float4*)(B + (size_t)(k0 + br) * N + bn + bc);
    Bs[br * 65 + bc + 0] = bv.x;
    Bs[br * 65 + bc + 1] = bv.y;
    Bs[br * 65 + bc + 2] = bv.z;
    Bs[br * 65 + bc + 3] = bv.w;
    __syncthreads();
#pragma unroll
    for (int kk = 0; kk < 16; ++kk) {
      float a0 = As[kk * 33 + ty * 2 + 0];
      float a1 = As[kk * 33 + ty * 2 + 1];
      float b0 = Bs[kk * 65 + tx * 4 + 0];
      float b1 = Bs[kk * 65 + tx * 4 + 1];
      float b2 = Bs[kk * 65 + tx * 4 + 2];
      float b3 = Bs[kk * 65 + tx * 4 + 3];
      acc[0][0] = fmaf(a0, b0, acc[0][0]); acc[0][1] = fmaf(a0, b1, acc[0][1]);
      acc[0][2] = fmaf(a0, b2, acc[0][2]); acc[0][3] = fmaf(a0, b3, acc[0][3]);
      acc[1][0] = fmaf(a1, b0, acc[1][0]); acc[1][1] = fmaf(a1, b1, acc[1][1]);
      acc[1][2] = fmaf(a1, b2, acc[1][2]); acc[1][3] = fmaf(a1, b3, acc[1][3]);
    }
    __syncthreads();
  }
#pragma unroll
  for (int i = 0; i < 2; ++i) {
    int m = bm + ty * 2 + i;
    if (m >= M) continue;
#pragma unroll
    for (int j = 0; j < 4; ++j) {
      C[(size_t)m * N + bn + tx * 4 + j] = acc[i][j];
    }
  }
}

// ---------------- K2: edge pass (adj fill + wT atomic + cg hist)  ||  Q GEMM ----------------
__global__ __launch_bounds__(256) void fill_and_Q(const int* __restrict__ srcI,
                                                  const int* __restrict__ dstI,
                                                  const int* __restrict__ batch,
                                                  int* __restrict__ cursor,
                                                  int* __restrict__ edst,
                                                  float* __restrict__ wT,
                                                  float* __restrict__ cgpad,
                                                  const float* __restrict__ Wg2,
                                                  const float* __restrict__ bg2,
                                                  const float* __restrict__ Wc1,
                                                  float* __restrict__ Q, int n_edges) {
  __shared__ float As[16 * 33];
  __shared__ float Bs[16 * 65];
  __shared__ int hist[64];
  int b = blockIdx.x;
  int t = threadIdx.x;
  if (b < EDGE_BLOCKS) {
    if (t < 64) hist[t] = 0;
    __syncthreads();
    int i = b * 256 + t;
    if (i < n_edges) {
      int s = srcI[i];
      int d = dstI[i];
      int bb = batch[d];
      int c = atomicAdd(&cursor[s], 1);
      edst[(size_t)s * CAP + c] = d;
      atomicAdd(&wT[(size_t)s * 64 + bb], 1.f);   // exact: integer-valued floats
      atomicAdd(&hist[bb], 1);
    }
    __syncthreads();
    if (t < 64 && hist[t] != 0) atomicAdd(&cgpad[t * CGS], (float)hist[t]);
  } else {
    gemm_stack_tile(Wg2, bg2, Wc1, Q, 513, 256, 512, 512, b - EDGE_BLOCKS, As, Bs, t);
  }
}

// ---------------- K3: compute_cT (1 node/block, 4-wave neighbor split)  ||  P GEMM ----------------
// cT[k][g] = wT[k][g] + sum_{d in N(k)} wT[d][g]
__global__ __launch_bounds__(256) void cT_and_P(const float* __restrict__ wT,
                                                const int* __restrict__ deg,
                                                const int* __restrict__ edst,
                                                float* __restrict__ cT,
                                                const float* __restrict__ Wg1,
                                                const float* __restrict__ bg1,
                                                const float* __restrict__ Q,
                                                float* __restrict__ P, int n_nodes) {
  __shared__ float As[16 * 33];
  __shared__ float Bs[16 * 65];
  __shared__ float red[4 * 64];
  int b = blockIdx.x;
  int t = threadIdx.x;
  if (b < n_nodes) {
    int node = b;
    int wave = t >> 6;
    int g = t & 63;
    int end = deg[node];
    const int* nb = edst + (size_t)node * CAP;
    float acc = 0.f;
    for (int i = wave; i < end; i += 4)
      acc += wT[(size_t)nb[i] * 64 + g];
    red[wave * 64 + g] = acc;
    __syncthreads();
    if (wave == 0) {
      float v = wT[(size_t)node * 64 + g] +
                red[g] + red[64 + g] + red[128 + g] + red[192 + g];
      cT[(size_t)node * 64 + g] = v;
    }
  } else {
    gemm_stack_tile(Wg1, bg1, Q, P, 513, 256, 512, 512, b - n_nodes, As, Bs, t);
  }
}

// ---------------- U-GEMM: Upart[c][g][n] = sum_{k in chunk c} cT[k][g]*x[k][n] ----------------
__global__ __launch_bounds__(256) void ugemm(const float* __restrict__ x,
                                             const float* __restrict__ cT,
                                             float* __restrict__ Upart) {
  __shared__ float sc[KCH][64];  // 32 KB
  int t = threadIdx.x;
  int k0 = blockIdx.y * KCH;
  int kmax = (N_NODES - k0) < KCH ? (N_NODES - k0) : KCH;  // 128 or 32; %4==0
  {
    const float4* src = (const float4*)(cT + (size_t)k0 * 64);
    float4* dst = (float4*)(&sc[0][0]);
    int limit4 = kmax * 16;
    for (int i = t; i < limit4; i += 256) dst[i] = src[i];
  }
  __syncthreads();
  int lane = t & 63;
  int slice = t >> 6;                 // g-range [slice*16, slice*16+16)
  int n2 = blockIdx.x * 64 + lane;    // float2 col 0..255
  const float2* x2 = (const float2*)x;
  float2 acc[16];
#pragma unroll
  for (int j = 0; j < 16; ++j) acc[j] = make_float2(0.f, 0.f);
  for (int kk = 0; kk < kmax; kk += 4) {
    float2 xv[4];
#pragma unroll
    for (int u = 0; u < 4; ++u)
      xv[u] = x2[(size_t)(k0 + kk + u) * 256 + n2];
#pragma unroll
    for (int u = 0; u < 4; ++u) {
      const float4* cp = (const float4*)&sc[kk + u][slice * 16];
      float4 c0 = cp[0], c1 = cp[1], c2 = cp[2], c3 = cp[3];
      float2 xu = xv[u];
      acc[0].x  = fmaf(c0.x, xu.x, acc[0].x);  acc[0].y  = fmaf(c0.x, xu.y, acc[0].y);
      acc[1].x  = fmaf(c0.y, xu.x, acc[1].x);  acc[1].y  = fmaf(c0.y, xu.y, acc[1].y);
      acc[2].x  = fmaf(c0.z, xu.x, acc[2].x);  acc[2].y  = fmaf(c0.z, xu.y, acc[2].y);
      acc[3].x  = fmaf(c0.w, xu.x, acc[3].x);  acc[3].y  = fmaf(c0.w, xu.y, acc[3].y);
      acc[4].x  = fmaf(c1.x, xu.x, acc[4].x);  acc[4].y  = fmaf(c1.x, xu.y, acc[4].y);
      acc[5].x  = fmaf(c1.y, xu.x, acc[5].x);  acc[5].y  = fmaf(c1.y, xu.y, acc[5].y);
      acc[6].x  = fmaf(c1.z, xu.x, acc[6].x);  acc[6].y  = fmaf(c1.z, xu.y, acc[6].y);
      acc[7].x  = fmaf(c1.w, xu.x, acc[7].x);  acc[7].y  = fmaf(c1.w, xu.y, acc[7].y);
      acc[8].x  = fmaf(c2.x, xu.x, acc[8].x);  acc[8].y  = fmaf(c2.x, xu.y, acc[8].y);
      acc[9].x  = fmaf(c2.y, xu.x, acc[9].x);  acc[9].y  = fmaf(c2.y, xu.y, acc[9].y);
      acc[10].x = fmaf(c2.z, xu.x, acc[10].x); acc[10].y = fmaf(c2.z, xu.y, acc[10].y);
      acc[11].x = fmaf(c2.w, xu.x, acc[11].x); acc[11].y = fmaf(c2.w, xu.y, acc[11].y);
      acc[12].x = fmaf(c3.x, xu.x, acc[12].x); acc[12].y = fmaf(c3.x, xu.y, acc[12].y);
      acc[13].x = fmaf(c3.y, xu.x, acc[13].x); acc[13].y = fmaf(c3.y, xu.y, acc[13].y);
      acc[14].x = fmaf(c3.z, xu.x, acc[14].x); acc[14].y = fmaf(c3.z, xu.y, acc[14].y);
      acc[15].x = fmaf(c3.w, xu.x, acc[15].x); acc[15].y = fmaf(c3.w, xu.y, acc[15].y);
    }
  }
  float2* up = (float2*)Upart;
#pragma unroll
  for (int j = 0; j < 16; ++j) {
    int g = slice * 16 + j;
    up[((size_t)blockIdx.y * 64 + g) * 256 + n2] = acc[j];
  }
}

// ---------------- Upart reduce: Ured[s][g][n] = sum_{c in split s} Upart[c][g][n] ----------------
__global__ __launch_bounds__(128) void reduce_U(const float* __restrict__ Upart,
                                                float* __restrict__ Ured) {
  int g = blockIdx.x;   // 0..63
  int s = blockIdx.y;   // 0..RSPLIT-1
  int t = threadIdx.x;  // 0..127 float4 over 512
  int c0 = s * CPS;
  int c1 = (c0 + CPS < NCHUNK) ? c0 + CPS : NCHUNK;
  const float4* up = (const float4*)Upart;
  float4 acc = make_float4(0.f, 0.f, 0.f, 0.f);
  for (int c = c0; c < c1; ++c) {
    float4 v = up[((size_t)c * 64 + g) * 128 + t];
    acc.x += v.x; acc.y += v.y; acc.z += v.z; acc.w += v.w;
  }
  ((float4*)Ured)[((size_t)s * 64 + g) * 128 + t] = acc;
}

// ---------------- fused head ----------------
// P[0:512] = Wc, P[512] = v1 ; Q[512] = v2 ; cg = ng + edge-hist(cgpad)
__global__ __launch_bounds__(256) void head(const float* __restrict__ Ured,
                                            const float* __restrict__ P,
                                            const float* __restrict__ Q,
                                            const float* __restrict__ ng,
                                            const float* __restrict__ cgpad,
                                            const float* __restrict__ bc1,
                                            const float* __restrict__ Wc2,
                                            const float* __restrict__ bc2,
                                            float* __restrict__ out) {
  int g = blockIdx.x;
  int j = threadIdx.x;
  const float* Wc = P;
  const float* v1 = P + (size_t)512 * 256;
  const float* v2 = Q + (size_t)512 * 256;
  __shared__ float p[512];
  float s0 = 0.f, s1 = 0.f;
#pragma unroll
  for (int s = 0; s < RSPLIT; ++s) {
    s0 += Ured[((size_t)s * 64 + g) * DIM + j];
    s1 += Ured[((size_t)s * 64 + g) * DIM + 256 + j];
  }
  p[j] = s0;
  p[j + 256] = s1;
  __syncthreads();
  float cg = ng[g] + cgpad[g * CGS];
  float acc = bc1[j] + cg * v1[j] + ng[g] * v2[j];
  for (int k = 0; k < 512; ++k) acc = fmaf(p[k], Wc[k * 256 + j], acc);
  float z = fmaxf(acc, 0.f);
  float part = z * Wc2[j];
  for (int off = 32; off > 0; off >>= 1) part += __shfl_down(part, off, 64);
  __shared__ float red[4];
  if ((j & 63) == 0) red[j >> 6] = part;
  __syncthreads();
  if (j == 0) {
    float tot = red[0] + red[1] + red[2] + red[3] + bc2[0];
    out[g] = 1.f / (1.f + expf(-tot));
  }
}

extern "C" void kernel_launch(void* const* d_in, const int* in_sizes, int n_in,
                              void* d_out, int out_size, void* d_ws, size_t ws_size,
                              hipStream_t stream) {
  const float* x    = (const float*)d_in[0];
  const int*   ei   = (const int*)d_in[1];
  const int*   batch= (const int*)d_in[2];
  const float* Wg1  = (const float*)d_in[3];
  const float* bg1  = (const float*)d_in[4];
  const float* Wg2  = (const float*)d_in[5];
  const float* bg2  = (const float*)d_in[6];
  const float* Wc1  = (const float*)d_in[7];
  const float* bc1  = (const float*)d_in[8];
  const float* Wc2  = (const float*)d_in[9];
  const float* bc2  = (const float*)d_in[10];
  float* out = (float*)d_out;

  int n_edges = in_sizes[1] / 2;
  int n_nodes = in_sizes[2];
  const int* srcI = ei;
  const int* dstI = ei + n_edges;

  char* ws = (char*)d_ws;
  size_t off = 0;
  auto alloc = [&](size_t bytes) { char* p = ws + off; off += (bytes + 255) & ~(size_t)255; return p; };
  float* wT    = (float*)alloc((size_t)N_NODES * 64 * sizeof(float));        // 5.12 MB
  float* cT    = (float*)alloc((size_t)N_NODES * 64 * sizeof(float));        // 5.12 MB
  float* Upart = (float*)alloc((size_t)NCHUNK * 64 * DIM * sizeof(float));   // 20.6 MB
  float* Ured  = (float*)alloc((size_t)RSPLIT * 64 * DIM * sizeof(float));   // 512 KB
  float* Q     = (float*)alloc((size_t)513 * 256 * sizeof(float));           // [Wg2;bg2]@Wc1
  float* P     = (float*)alloc((size_t)513 * 256 * sizeof(float));           // [Wg1;bg1]@Q0
  float* ng    = (float*)alloc(NG * sizeof(float));
  float* cgpad = (float*)alloc(NG * CGS * sizeof(float));
  int* cursor  = (int*)alloc(N_NODES * sizeof(int));                         // degree after fill
  int* edst    = (int*)alloc((size_t)N_NODES * CAP * sizeof(int));           // 5.12 MB padded adj

  // K1: wT one-hot + cursor zero + ng/cgpad init
  node_init<<<NODE_BLOCKS, 256, 0, stream>>>(batch, wT, cursor, ng, cgpad, n_nodes);
  // K2: edge pass (adjacency fill + wT accumulate + cg hist) || Q GEMM
  fill_and_Q<<<EDGE_BLOCKS + GEMM_TILES, 256, 0, stream>>>(srcI, dstI, batch, cursor, edst,
                                                           wT, cgpad, Wg2, bg2, Wc1, Q, n_edges);
  // K3: compute_cT (1 node/block, 4-wave split) || P GEMM
  cT_and_P<<<N_NODES + GEMM_TILES, 256, 0, stream>>>(wT, cursor, edst, cT,
                                                     Wg1, bg1, Q, P, n_nodes);
  // K4: U partials
  ugemm<<<dim3(4, NCHUNK), 256, 0, stream>>>(x, cT, Upart);
  // K5: reduce partials
  reduce_U<<<dim3(64, RSPLIT), 128, 0, stream>>>(Upart, Ured);
  // K6: head
  head<<<NG, 256, 0, stream>>>(Ured, P, Q, ng, cgpad, bc1, Wc2, bc2, out);
}

// Round 15
// 269.542 us; speedup vs baseline: 1.0615x; 1.0615x over previous
//
#include <hip/hip_runtime.h>
#include <math.h>

constexpr int N_NODES = 20000;
constexpr int DIM = 512;       // NODE_DIM == HIDDEN
constexpr int NG = 64;
constexpr int CAP = 64;        // padded adjacency capacity (avg deg 16, max ~40, >12 sigma)
constexpr int KCH = 128;       // U-GEMM k-chunk
constexpr int NCHUNK = (N_NODES + KCH - 1) / KCH;  // 157 (last chunk kmax=32, %4==0)
constexpr int RSPLIT = 4;
constexpr int CPS = (NCHUNK + RSPLIT - 1) / RSPLIT; // 40
constexpr int CGS = 32;        // cgpad stride (floats) -> 128B, one cacheline per graph
constexpr int NODE_BLOCKS = (N_NODES + 3) / 4;      // 5000
constexpr int GEMM_TILES = 17 * 4;                  // 68 tiles for 513x256 output
constexpr int EDGE_BLOCKS = 1250;                   // 320000 edges / 256

// ---------------- misc ----------------
__device__ __forceinline__ int lower_bound_i(const int* __restrict__ a, int n, int v) {
  int lo = 0, hi = n;
  while (lo < hi) {
    int mid = (lo + hi) >> 1;
    if (a[mid] < v) lo = mid + 1; else hi = mid;
  }
  return lo;
}

// wT[j][g] = one-hot(batch[j]); cursor[j]=0; block 0: ng[g], cgpad zero
__global__ __launch_bounds__(256) void node_init(const int* __restrict__ batch,
                                                 float* __restrict__ wT,
                                                 int* __restrict__ cursor,
                                                 float* __restrict__ ng,
                                                 float* __restrict__ cgpad, int n_nodes) {
  int node = blockIdx.x * 4 + (threadIdx.x >> 6);
  int g = threadIdx.x & 63;
  if (node < n_nodes) {
    int b = batch[node];
    wT[(size_t)node * 64 + g] = (g == b) ? 1.f : 0.f;
    if (g == 0) cursor[node] = 0;
  }
  if (blockIdx.x == 0 && threadIdx.x < 64) {
    int gg = threadIdx.x;
    int s0 = lower_bound_i(batch, n_nodes, gg);
    int e0 = lower_bound_i(batch, n_nodes, gg + 1);
    ng[gg] = (float)(e0 - s0);
    cgpad[gg * CGS] = 0.f;
  }
}

// ---- shared-memory GEMM tile body: C[M,N] = [A0; extraRow] @ B, one 32x64 tile ----
__device__ void gemm_stack_tile(const float* __restrict__ A0, const float* __restrict__ extra,
                                const float* __restrict__ B, float* __restrict__ C,
                                int M, int N, int K, int R0, int tile,
                                float* As, float* Bs, int tid) {
  int bm = (tile >> 2) * 32;   // 0..16 -> 32-row tile
  int bn = (tile & 3) * 64;    // 0..3  -> 64-col tile
  int tx = tid & 15;
  int ty = tid >> 4;
  int ar = tid >> 3;
  int ac = (tid & 7) * 2;
  int br = tid >> 4;
  int bc = (tid & 15) * 4;
  float acc[2][4] = {};
  for (int k0 = 0; k0 < K; k0 += 16) {
    int row = bm + ar;
    float2 av = make_float2(0.f, 0.f);
    if (row < R0)       av = *(const float2*)(A0 + (size_t)row * K + k0 + ac);
    else if (row == R0) av = *(const float2*)(extra + k0 + ac);
    As[(ac + 0) * 33 + ar] = av.x;
    As[(ac + 1) * 33 + ar] = av.y;
    float4 bv = *(const float4*)(B + (size_t)(k0 + br) * N + bn + bc);
    Bs[br * 65 + bc + 0] = bv.x;
    Bs[br * 65 + bc + 1] = bv.y;
    Bs[br * 65 + bc + 2] = bv.z;
    Bs[br * 65 + bc + 3] = bv.w;
    __syncthreads();
#pragma unroll
    for (int kk = 0; kk < 16; ++kk) {
      float a0 = As[kk * 33 + ty * 2 + 0];
      float a1 = As[kk * 33 + ty * 2 + 1];
      float b0 = Bs[kk * 65 + tx * 4 + 0];
      float b1 = Bs[kk * 65 + tx * 4 + 1];
      float b2 = Bs[kk * 65 + tx * 4 + 2];
      float b3 = Bs[kk * 65 + tx * 4 + 3];
      acc[0][0] = fmaf(a0, b0, acc[0][0]); acc[0][1] = fmaf(a0, b1, acc[0][1]);
      acc[0][2] = fmaf(a0, b2, acc[0][2]); acc[0][3] = fmaf(a0, b3, acc[0][3]);
      acc[1][0] = fmaf(a1, b0, acc[1][0]); acc[1][1] = fmaf(a1, b1, acc[1][1]);
      acc[1][2] = fmaf(a1, b2, acc[1][2]); acc[1][3] = fmaf(a1, b3, acc[1][3]);
    }
    __syncthreads();
  }
#pragma unroll
  for (int i = 0; i < 2; ++i) {
    int m = bm + ty * 2 + i;
    if (m >= M) continue;
#pragma unroll
    for (int j = 0; j < 4; ++j) {
      C[(size_t)m * N + bn + tx * 4 + j] = acc[i][j];
    }
  }
}

// ---------------- K2: edge pass (adj fill + wT atomic + cg hist)  ||  Q GEMM ----------------
__global__ __launch_bounds__(256) void fill_and_Q(const int* __restrict__ srcI,
                                                  const int* __restrict__ dstI,
                                                  const int* __restrict__ batch,
                                                  int* __restrict__ cursor,
                                                  int* __restrict__ edst,
                                                  float* __restrict__ wT,
                                                  float* __restrict__ cgpad,
                                                  const float* __restrict__ Wg2,
                                                  const float* __restrict__ bg2,
                                                  const float* __restrict__ Wc1,
                                                  float* __restrict__ Q, int n_edges) {
  __shared__ float As[16 * 33];
  __shared__ float Bs[16 * 65];
  __shared__ int hist[64];
  int b = blockIdx.x;
  int t = threadIdx.x;
  if (b < EDGE_BLOCKS) {
    if (t < 64) hist[t] = 0;
    __syncthreads();
    int i = b * 256 + t;
    if (i < n_edges) {
      int s = srcI[i];
      int d = dstI[i];
      int bb = batch[d];
      int c = atomicAdd(&cursor[s], 1);
      edst[(size_t)s * CAP + c] = d;
      atomicAdd(&wT[(size_t)s * 64 + bb], 1.f);   // exact: integer-valued floats
      atomicAdd(&hist[bb], 1);
    }
    __syncthreads();
    if (t < 64 && hist[t] != 0) atomicAdd(&cgpad[t * CGS], (float)hist[t]);
  } else {
    gemm_stack_tile(Wg2, bg2, Wc1, Q, 513, 256, 512, 512, b - EDGE_BLOCKS, As, Bs, t);
  }
}

// ---------------- K3: compute_cT (4 nodes/block, wave/node, x8 ILP)  ||  P GEMM ----------------
// cT[k][g] = wT[k][g] + sum_{d in N(k)} wT[d][g]
__global__ __launch_bounds__(256) void cT_and_P(const float* __restrict__ wT,
                                                const int* __restrict__ deg,
                                                const int* __restrict__ edst,
                                                float* __restrict__ cT,
                                                const float* __restrict__ Wg1,
                                                const float* __restrict__ bg1,
                                                const float* __restrict__ Q,
                                                float* __restrict__ P, int n_nodes) {
  __shared__ float As[16 * 33];
  __shared__ float Bs[16 * 65];
  int b = blockIdx.x;
  int t = threadIdx.x;
  if (b < NODE_BLOCKS) {
    int node = b * 4 + (t >> 6);
    int g = t & 63;
    if (node >= n_nodes) return;
    float acc = wT[(size_t)node * 64 + g];
    int end = deg[node];
    const int* nb = edst + (size_t)node * CAP;
    int i = 0;
    for (; i + 7 < end; i += 8) {
      int d0 = nb[i], d1 = nb[i + 1], d2 = nb[i + 2], d3 = nb[i + 3];
      int d4 = nb[i + 4], d5 = nb[i + 5], d6 = nb[i + 6], d7 = nb[i + 7];
      float v0 = wT[(size_t)d0 * 64 + g], v1 = wT[(size_t)d1 * 64 + g];
      float v2 = wT[(size_t)d2 * 64 + g], v3 = wT[(size_t)d3 * 64 + g];
      float v4 = wT[(size_t)d4 * 64 + g], v5 = wT[(size_t)d5 * 64 + g];
      float v6 = wT[(size_t)d6 * 64 + g], v7 = wT[(size_t)d7 * 64 + g];
      acc += ((v0 + v1) + (v2 + v3)) + ((v4 + v5) + (v6 + v7));
    }
    for (; i + 3 < end; i += 4) {
      int d0 = nb[i], d1 = nb[i + 1], d2 = nb[i + 2], d3 = nb[i + 3];
      acc += wT[(size_t)d0 * 64 + g] + wT[(size_t)d1 * 64 + g] +
             wT[(size_t)d2 * 64 + g] + wT[(size_t)d3 * 64 + g];
    }
    for (; i < end; ++i) acc += wT[(size_t)nb[i] * 64 + g];
    cT[(size_t)node * 64 + g] = acc;
  } else {
    gemm_stack_tile(Wg1, bg1, Q, P, 513, 256, 512, 512, b - NODE_BLOCKS, As, Bs, t);
  }
}

// ---------------- U-GEMM: Upart[c][g][n] = sum_{k in chunk c} cT[k][g]*x[k][n] ----------------
__global__ __launch_bounds__(256) void ugemm(const float* __restrict__ x,
                                             const float* __restrict__ cT,
                                             float* __restrict__ Upart) {
  __shared__ float sc[KCH][64];  // 32 KB
  int t = threadIdx.x;
  int k0 = blockIdx.y * KCH;
  int kmax = (N_NODES - k0) < KCH ? (N_NODES - k0) : KCH;  // 128 or 32; %4==0
  {
    const float4* src = (const float4*)(cT + (size_t)k0 * 64);
    float4* dst = (float4*)(&sc[0][0]);
    int limit4 = kmax * 16;
    for (int i = t; i < limit4; i += 256) dst[i] = src[i];
  }
  __syncthreads();
  int lane = t & 63;
  int slice = t >> 6;                 // g-range [slice*16, slice*16+16)
  int n2 = blockIdx.x * 64 + lane;    // float2 col 0..255
  const float2* x2 = (const float2*)x;
  float2 acc[16];
#pragma unroll
  for (int j = 0; j < 16; ++j) acc[j] = make_float2(0.f, 0.f);
  for (int kk = 0; kk < kmax; kk += 4) {
    float2 xv[4];
#pragma unroll
    for (int u = 0; u < 4; ++u)
      xv[u] = x2[(size_t)(k0 + kk + u) * 256 + n2];
#pragma unroll
    for (int u = 0; u < 4; ++u) {
      const float4* cp = (const float4*)&sc[kk + u][slice * 16];
      float4 c0 = cp[0], c1 = cp[1], c2 = cp[2], c3 = cp[3];
      float2 xu = xv[u];
      acc[0].x  = fmaf(c0.x, xu.x, acc[0].x);  acc[0].y  = fmaf(c0.x, xu.y, acc[0].y);
      acc[1].x  = fmaf(c0.y, xu.x, acc[1].x);  acc[1].y  = fmaf(c0.y, xu.y, acc[1].y);
      acc[2].x  = fmaf(c0.z, xu.x, acc[2].x);  acc[2].y  = fmaf(c0.z, xu.y, acc[2].y);
      acc[3].x  = fmaf(c0.w, xu.x, acc[3].x);  acc[3].y  = fmaf(c0.w, xu.y, acc[3].y);
      acc[4].x  = fmaf(c1.x, xu.x, acc[4].x);  acc[4].y  = fmaf(c1.x, xu.y, acc[4].y);
      acc[5].x  = fmaf(c1.y, xu.x, acc[5].x);  acc[5].y  = fmaf(c1.y, xu.y, acc[5].y);
      acc[6].x  = fmaf(c1.z, xu.x, acc[6].x);  acc[6].y  = fmaf(c1.z, xu.y, acc[6].y);
      acc[7].x  = fmaf(c1.w, xu.x, acc[7].x);  acc[7].y  = fmaf(c1.w, xu.y, acc[7].y);
      acc[8].x  = fmaf(c2.x, xu.x, acc[8].x);  acc[8].y  = fmaf(c2.x, xu.y, acc[8].y);
      acc[9].x  = fmaf(c2.y, xu.x, acc[9].x);  acc[9].y  = fmaf(c2.y, xu.y, acc[9].y);
      acc[10].x = fmaf(c2.z, xu.x, acc[10].x); acc[10].y = fmaf(c2.z, xu.y, acc[10].y);
      acc[11].x = fmaf(c2.w, xu.x, acc[11].x); acc[11].y = fmaf(c2.w, xu.y, acc[11].y);
      acc[12].x = fmaf(c3.x, xu.x, acc[12].x); acc[12].y = fmaf(c3.x, xu.y, acc[12].y);
      acc[13].x = fmaf(c3.y, xu.x, acc[13].x); acc[13].y = fmaf(c3.y, xu.y, acc[13].y);
      acc[14].x = fmaf(c3.z, xu.x, acc[14].x); acc[14].y = fmaf(c3.z, xu.y, acc[14].y);
      acc[15].x = fmaf(c3.w, xu.x, acc[15].x); acc[15].y = fmaf(c3.w, xu.y, acc[15].y);
    }
  }
  float2* up = (float2*)Upart;
#pragma unroll
  for (int j = 0; j < 16; ++j) {
    int g = slice * 16 + j;
    up[((size_t)blockIdx.y * 64 + g) * 256 + n2] = acc[j];
  }
}

// ---------------- Upart reduce: Ured[s][g][n] = sum_{c in split s} Upart[c][g][n] ----------------
__global__ __launch_bounds__(128) void reduce_U(const float* __restrict__ Upart,
                                                float* __restrict__ Ured) {
  int g = blockIdx.x;   // 0..63
  int s = blockIdx.y;   // 0..RSPLIT-1
  int t = threadIdx.x;  // 0..127 float4 over 512
  int c0 = s * CPS;
  int c1 = (c0 + CPS < NCHUNK) ? c0 + CPS : NCHUNK;
  const float4* up = (const float4*)Upart;
  float4 acc = make_float4(0.f, 0.f, 0.f, 0.f);
  for (int c = c0; c < c1; ++c) {
    float4 v = up[((size_t)c * 64 + g) * 128 + t];
    acc.x += v.x; acc.y += v.y; acc.z += v.z; acc.w += v.w;
  }
  ((float4*)Ured)[((size_t)s * 64 + g) * 128 + t] = acc;
}

// ---------------- fused head ----------------
// P[0:512] = Wc, P[512] = v1 ; Q[512] = v2 ; cg = ng + edge-hist(cgpad)
__global__ __launch_bounds__(256) void head(const float* __restrict__ Ured,
                                            const float* __restrict__ P,
                                            const float* __restrict__ Q,
                                            const float* __restrict__ ng,
                                            const float* __restrict__ cgpad,
                                            const float* __restrict__ bc1,
                                            const float* __restrict__ Wc2,
                                            const float* __restrict__ bc2,
                                            float* __restrict__ out) {
  int g = blockIdx.x;
  int j = threadIdx.x;
  const float* Wc = P;
  const float* v1 = P + (size_t)512 * 256;
  const float* v2 = Q + (size_t)512 * 256;
  __shared__ float p[512];
  float s0 = 0.f, s1 = 0.f;
#pragma unroll
  for (int s = 0; s < RSPLIT; ++s) {
    s0 += Ured[((size_t)s * 64 + g) * DIM + j];
    s1 += Ured[((size_t)s * 64 + g) * DIM + 256 + j];
  }
  p[j] = s0;
  p[j + 256] = s1;
  __syncthreads();
  float cg = ng[g] + cgpad[g * CGS];
  float acc = bc1[j] + cg * v1[j] + ng[g] * v2[j];
  for (int k = 0; k < 512; ++k) acc = fmaf(p[k], Wc[k * 256 + j], acc);
  float z = fmaxf(acc, 0.f);
  float part = z * Wc2[j];
  for (int off = 32; off > 0; off >>= 1) part += __shfl_down(part, off, 64);
  __shared__ float red[4];
  if ((j & 63) == 0) red[j >> 6] = part;
  __syncthreads();
  if (j == 0) {
    float tot = red[0] + red[1] + red[2] + red[3] + bc2[0];
    out[g] = 1.f / (1.f + expf(-tot));
  }
}

extern "C" void kernel_launch(void* const* d_in, const int* in_sizes, int n_in,
                              void* d_out, int out_size, void* d_ws, size_t ws_size,
                              hipStream_t stream) {
  const float* x    = (const float*)d_in[0];
  const int*   ei   = (const int*)d_in[1];
  const int*   batch= (const int*)d_in[2];
  const float* Wg1  = (const float*)d_in[3];
  const float* bg1  = (const float*)d_in[4];
  const float* Wg2  = (const float*)d_in[5];
  const float* bg2  = (const float*)d_in[6];
  const float* Wc1  = (const float*)d_in[7];
  const float* bc1  = (const float*)d_in[8];
  const float* Wc2  = (const float*)d_in[9];
  const float* bc2  = (const float*)d_in[10];
  float* out = (float*)d_out;

  int n_edges = in_sizes[1] / 2;
  int n_nodes = in_sizes[2];
  const int* srcI = ei;
  const int* dstI = ei + n_edges;

  char* ws = (char*)d_ws;
  size_t off = 0;
  auto alloc = [&](size_t bytes) { char* p = ws + off; off += (bytes + 255) & ~(size_t)255; return p; };
  float* wT    = (float*)alloc((size_t)N_NODES * 64 * sizeof(float));        // 5.12 MB
  float* cT    = (float*)alloc((size_t)N_NODES * 64 * sizeof(float));        // 5.12 MB
  float* Upart = (float*)alloc((size_t)NCHUNK * 64 * DIM * sizeof(float));   // 20.6 MB
  float* Ured  = (float*)alloc((size_t)RSPLIT * 64 * DIM * sizeof(float));   // 512 KB
  float* Q     = (float*)alloc((size_t)513 * 256 * sizeof(float));           // [Wg2;bg2]@Wc1
  float* P     = (float*)alloc((size_t)513 * 256 * sizeof(float));           // [Wg1;bg1]@Q0
  float* ng    = (float*)alloc(NG * sizeof(float));
  float* cgpad = (float*)alloc(NG * CGS * sizeof(float));
  int* cursor  = (int*)alloc(N_NODES * sizeof(int));                         // degree after fill
  int* edst    = (int*)alloc((size_t)N_NODES * CAP * sizeof(int));           // 5.12 MB padded adj

  // K1: wT one-hot + cursor zero + ng/cgpad init
  node_init<<<NODE_BLOCKS, 256, 0, stream>>>(batch, wT, cursor, ng, cgpad, n_nodes);
  // K2: edge pass (adjacency fill + wT accumulate + cg hist) || Q GEMM
  fill_and_Q<<<EDGE_BLOCKS + GEMM_TILES, 256, 0, stream>>>(srcI, dstI, batch, cursor, edst,
                                                           wT, cgpad, Wg2, bg2, Wc1, Q, n_edges);
  // K3: compute_cT (4 nodes/block, x8 ILP) || P GEMM
  cT_and_P<<<NODE_BLOCKS + GEMM_TILES, 256, 0, stream>>>(wT, cursor, edst, cT,
                                                         Wg1, bg1, Q, P, n_nodes);
  // K4: U partials
  ugemm<<<dim3(4, NCHUNK), 256, 0, stream>>>(x, cT, Upart);
  // K5: reduce partials
  reduce_U<<<dim3(64, RSPLIT), 128, 0, stream>>>(Upart, Ured);
  // K6: head
  head<<<NG, 256, 0, stream>>>(Ured, P, Q, ng, cgpad, bc1, Wc2, bc2, out);
}